// Round 12
// baseline (1109.811 us; speedup 1.0000x reference)
//
#include <hip/hip_runtime.h>

typedef __attribute__((ext_vector_type(8))) short short8;
typedef __attribute__((ext_vector_type(4))) float f32x4;

#define NSTEPS 16

__device__ __forceinline__ unsigned short bf16rne(float f) {
  unsigned int u = __float_as_uint(f);
  u += 0x7FFFu + ((u >> 16) & 1u);
  return (unsigned short)(u >> 16);
}

#if __has_builtin(__builtin_amdgcn_cvt_pk_bf16_f32)
typedef __attribute__((ext_vector_type(2))) __bf16 v2bf16;
__device__ __forceinline__ unsigned int pk2(float a, float b) {
  v2bf16 t = __builtin_amdgcn_cvt_pk_bf16_f32(a, b);
  unsigned int r;
  __builtin_memcpy(&r, &t, 4);
  return r;
}
#else
__device__ __forceinline__ unsigned int pk2(float a, float b) {
  unsigned int ua = __float_as_uint(a), ub = __float_as_uint(b);
  ua += 0x7FFFu + ((ua >> 16) & 1u);
  ub += 0x7FFFu + ((ub >> 16) & 1u);
  return (ua >> 16) | (ub & 0xFFFF0000u);
}
#endif

__device__ __forceinline__ float tanh_fast(float x) {
  // tanh(x) = 1 - 2/(e^{2x}+1); e->inf => 1, e->0 => -1 (no clamp needed)
  float e = __builtin_amdgcn_exp2f(x * 2.8853900817779268f);
  return __builtin_fmaf(-2.0f, __builtin_amdgcn_rcpf(e + 1.0f), 1.0f);
}

// Pre-shuffle fp32 weights -> bf16 MFMA fragments (B-frag of W == A-frag of W^T).
// lane holds W[k = 32*ks + 8*(lane>>4) + j][c = 16*t + (lane&15)], j=0..7
__global__ void ffjord_setup(const float* __restrict__ W1a, const float* __restrict__ W2a,
                             const float* __restrict__ W3a, const float* __restrict__ W1b,
                             const float* __restrict__ W2b, const float* __restrict__ W3b,
                             unsigned short* __restrict__ ws) {
  int gid = blockIdx.x * blockDim.x + threadIdx.x;   // 0..24575
  int bij = gid / 12288;
  int r = gid - bij * 12288;
  const float* W1 = bij ? W1b : W1a;
  const float* W2 = bij ? W2b : W2a;
  const float* W3 = bij ? W3b : W3a;
  unsigned short* o = ws + bij * 98304;
  const float* src;
  int kstride;
  if (r < 2048) {                 // W1f
    int lane = r & 63, nt = (r >> 6) & 15, ks = r >> 10;
    int k0 = ks * 32 + (lane >> 4) * 8, n = nt * 16 + (lane & 15);
    src = W1 + k0 * 256 + n; kstride = 256; o += r * 8;
  } else if (r < 10240) {         // W2f
    int rr = r - 2048;
    int lane = rr & 63, nt = (rr >> 6) & 15, ks = rr >> 10;
    int k0 = ks * 32 + (lane >> 4) * 8, n = nt * 16 + (lane & 15);
    src = W2 + k0 * 256 + n; kstride = 256; o += 16384 + rr * 8;
  } else {                        // W3f
    int rr = r - 10240;
    int lane = rr & 63, nt = (rr >> 6) & 3, ks = rr >> 8;
    int k0 = ks * 32 + (lane >> 4) * 8, n = nt * 16 + (lane & 15);
    src = W3 + k0 * 64 + n; kstride = 64; o += 81920 + rr * 8;
  }
  #pragma unroll
  for (int j = 0; j < 8; j++) o[j] = bf16rne(src[j * kstride]);
}

// Grid 512 x 512 threads (8 waves): TWO blocks per CU = two independent
// barrier domains that overlap phases (the ~300-600 cyc/stage barrier drain
// of the single-block layouts is the target). Each block owns 8 batch rows
// (row-slots 8-15 of each MFMA tile are benign garbage: tanh saturates,
// MFMA columns don't mix, x/out guarded). Every wave owns 2 m-tiles of
// L1/L2 (fragment reads shared -> per-CU LDS reads match the 16-row
// single-block layout). Waves 0-3 additionally run full-K layer 3 + RK:
// W3 frags from GLOBAL (L1/L2-cached, vmem pipe, not LDS), k-history in
// LDS kbuf (R10 trick, avoids spill), y-slice in 4 regs, next-stage z
// emitted directly as bf16 A-frags. 3 barriers/stage.
__global__ __launch_bounds__(512, 4) void ffjord_main(
    const float* __restrict__ x, float* __restrict__ out,
    const unsigned short* __restrict__ ws,
    const float* __restrict__ W1a, const float* __restrict__ b1a,
    const float* __restrict__ b2a, const float* __restrict__ b3a,
    const float* __restrict__ W1b, const float* __restrict__ b1b,
    const float* __restrict__ b2b, const float* __restrict__ b3b) {
  // zA: 8 groups of (16 row-slots x 8 j) ushorts, each group padded 256B->272B
  __shared__ __align__(16) unsigned short zA[1088];
  __shared__ __align__(16) unsigned short h1A[4096];   // [g8][slot16][j8]
  __shared__ __align__(16) unsigned short h2A[4096];
  __shared__ __align__(16) float kbuf[5][1024];        // k_0..k_4 (waves 0-3, 20 KB)

  const int tid = threadIdx.x;
  const int wave = tid >> 6;        // 0..7
  const int lane = tid & 63;
  const int cl = lane & 15;
  const int qd = lane >> 4;
  const int row0 = blockIdx.x * 8;

  // MLP: wave w owns m-tiles 2w, 2w+1 -> hidden dims [32w, 32w+32)
  int hoff[2];
  #pragma unroll
  for (int t = 0; t < 2; t++) {
    int c = (wave * 2 + t) * 16 + qd * 4;
    hoff[t] = (c >> 5) * 512 + ((c & 31) >> 3) * 128 + cl * 8 + (c & 7);
  }
  // z A-frag read base (second frag at +544 ushorts)
  const int zrb = qd * 136 + cl * 8;
  // L3/RK (waves 0-3): tile t3 = wave -> dims dl3..dl3+3 of row-slot cl
  const int t3 = wave;
  const int dl3 = t3 * 16 + qd * 4;
  // z-frag write slot for those 4 dims (b64-aligned)
  const int zw = (2 * t3 + (qd >> 1)) * 136 + cl * 8 + 4 * (qd & 1);

  const float hstep = 1.0f / 16.0f;

  f32x4 yc;           // private y slice (4 dims x 1 row-slot), waves 0-3

  // A2[s] = DOPRI a_{s+1,j} coefficients (z for stage s+1 built at stage s)
  const float A2[5][5] = {
      {1.f / 5.f, 0.f, 0.f, 0.f, 0.f},
      {3.f / 40.f, 9.f / 40.f, 0.f, 0.f, 0.f},
      {44.f / 45.f, -56.f / 15.f, 32.f / 9.f, 0.f, 0.f},
      {19372.f / 6561.f, -25360.f / 2187.f, 64448.f / 6561.f, -212.f / 729.f, 0.f},
      {9017.f / 3168.f, -355.f / 33.f, 46732.f / 5247.f, 49.f / 176.f, -5103.f / 18656.f}};
  const float CT[6] = {0.0f, 0.2f, 0.3f, 0.8f, 8.0f / 9.0f, 1.0f};
  const float BW0 = 35.f / 384.f, BW2 = 500.f / 1113.f, BW3 = 125.f / 192.f,
              BW4 = -2187.f / 6784.f, BW5 = 11.f / 84.f;

  for (int bij = 0; bij < 2; bij++) {
    const unsigned short* wsb = ws + bij * 98304;
    const float* W1 = bij ? W1b : W1a;
    const float* b1 = bij ? b1b : b1a;
    const float* b2 = bij ? b2b : b2a;
    const float* b3 = bij ? b3b : b3a;

    // all waves: MLP register state (2 tiles)
    f32x4 b1c[2], w1t4[2], b2c[2];
    short8 w1f[2][2], w2f[8][2];
    {
      const short8* w1p = (const short8*)wsb;
      const short8* w2p = (const short8*)(wsb + 16384);
      #pragma unroll
      for (int t = 0; t < 2; t++) {
        int c = (wave * 2 + t) * 16 + qd * 4;
        b1c[t] = *(const f32x4*)(b1 + c);
        w1t4[t] = *(const f32x4*)(W1 + 64 * 256 + c);
        b2c[t] = *(const f32x4*)(b2 + c);
        #pragma unroll
        for (int ks = 0; ks < 2; ks++)
          w1f[ks][t] = w1p[(ks * 16 + wave * 2 + t) * 64 + lane];
        #pragma unroll
        for (int ks = 0; ks < 8; ks++)
          w2f[ks][t] = w2p[(ks * 16 + wave * 2 + t) * 64 + lane];
      }
    }
    // L3/RK waves: b3 slice; y init + z0 publish on bijector 0
    f32x4 b3c;
    if (wave < 4) {
      b3c = *(const f32x4*)(b3 + dl3);
      if (bij == 0) {
        if (cl < 8) yc = *(const f32x4*)(x + (row0 + cl) * 64 + dl3);
        else { yc[0] = 0.f; yc[1] = 0.f; yc[2] = 0.f; yc[3] = 0.f; }
        uint2 pv;
        pv.x = pk2(yc[0], yc[1]);
        pv.y = pk2(yc[2], yc[3]);
        *(uint2*)(zA + zw) = pv;
      }
      // bij 1: z0 = y already published by the last stage-5 emit below
    }
    __syncthreads();

    const short8* w3p = (const short8*)(wsb + 81920);

    for (int step = 0; step < NSTEPS; step++) {
      float stepf = (float)step;
      #pragma unroll
      for (int s = 0; s < 6; s++) {
        float ts = (stepf + CT[s]) * hstep;

        // ---- layer 1 (all waves): h1 = tanh(W1^T z_s + b1 + t*W1t), K=64,
        // two m-tiles sharing the zA fragment reads
        {
          short8 a0 = *(const short8*)(zA + zrb);
          short8 a1 = *(const short8*)(zA + zrb + 544);
          #pragma unroll
          for (int t = 0; t < 2; t++) {
            f32x4 acc;
            #pragma unroll
            for (int r = 0; r < 4; r++)
              acc[r] = __builtin_fmaf(ts, w1t4[t][r], b1c[t][r]);
            acc = __builtin_amdgcn_mfma_f32_16x16x32_bf16(w1f[0][t], a0, acc, 0, 0, 0);
            acc = __builtin_amdgcn_mfma_f32_16x16x32_bf16(w1f[1][t], a1, acc, 0, 0, 0);
            uint2 pv;
            pv.x = pk2(tanh_fast(acc[0]), tanh_fast(acc[1]));
            pv.y = pk2(tanh_fast(acc[2]), tanh_fast(acc[3]));
            *(uint2*)(h1A + hoff[t]) = pv;
          }
        }
        __syncthreads();

        // ---- layer 2 (all waves): h2 = tanh(W2^T h1 + b2), K=256,
        // two m-tiles share each h1 fragment read; 2 chains per tile
        {
          f32x4 a0A = b2c[0], a1A = b2c[1];
          f32x4 zf; zf[0] = 0.f; zf[1] = 0.f; zf[2] = 0.f; zf[3] = 0.f;
          f32x4 a0B = zf, a1B = zf;
          #pragma unroll
          for (int ks = 0; ks < 4; ks++) {
            short8 hb = ((const short8*)h1A)[ks * 64 + lane];
            a0A = __builtin_amdgcn_mfma_f32_16x16x32_bf16(w2f[ks][0], hb, a0A, 0, 0, 0);
            a1A = __builtin_amdgcn_mfma_f32_16x16x32_bf16(w2f[ks][1], hb, a1A, 0, 0, 0);
          }
          #pragma unroll
          for (int ks = 4; ks < 8; ks++) {
            short8 hb = ((const short8*)h1A)[ks * 64 + lane];
            a0B = __builtin_amdgcn_mfma_f32_16x16x32_bf16(w2f[ks][0], hb, a0B, 0, 0, 0);
            a1B = __builtin_amdgcn_mfma_f32_16x16x32_bf16(w2f[ks][1], hb, a1B, 0, 0, 0);
          }
          uint2 pv;
          pv.x = pk2(tanh_fast(a0A[0] + a0B[0]), tanh_fast(a0A[1] + a0B[1]));
          pv.y = pk2(tanh_fast(a0A[2] + a0B[2]), tanh_fast(a0A[3] + a0B[3]));
          *(uint2*)(h2A + hoff[0]) = pv;
          pv.x = pk2(tanh_fast(a1A[0] + a1B[0]), tanh_fast(a1A[1] + a1B[1]));
          pv.y = pk2(tanh_fast(a1A[2] + a1B[2]), tanh_fast(a1A[3] + a1B[3]));
          *(uint2*)(h2A + hoff[1]) = pv;
        }
        __syncthreads();

        // ---- layer 3 + RK (waves 0-3): k_s = W3^T h2 + b3, full K=256,
        // W3 frags from global (cached); k-history in kbuf; emit z_{s+1}
        // (or update y) directly as bf16 A-frags.
        if (wave < 4) {
          f32x4 accP = b3c;
          f32x4 accQ; accQ[0] = 0.f; accQ[1] = 0.f; accQ[2] = 0.f; accQ[3] = 0.f;
          #pragma unroll
          for (int ks = 0; ks < 8; ks += 2) {
            short8 hb0 = ((const short8*)h2A)[ks * 64 + lane];
            short8 wf0 = w3p[(ks * 4 + t3) * 64 + lane];
            short8 hb1 = ((const short8*)h2A)[(ks + 1) * 64 + lane];
            short8 wf1 = w3p[((ks + 1) * 4 + t3) * 64 + lane];
            accP = __builtin_amdgcn_mfma_f32_16x16x32_bf16(wf0, hb0, accP, 0, 0, 0);
            accQ = __builtin_amdgcn_mfma_f32_16x16x32_bf16(wf1, hb1, accQ, 0, 0, 0);
          }
          f32x4 kc;
          #pragma unroll
          for (int r = 0; r < 4; r++) kc[r] = accP[r] + accQ[r];
          if (s < 5) *(f32x4*)(&kbuf[s][tid * 4]) = kc;   // k_5 never re-read

          f32x4 z;
          if (s < 5) {
            #pragma unroll
            for (int r = 0; r < 4; r++)
              z[r] = __builtin_fmaf(hstep * A2[s][s], kc[r], yc[r]);
            #pragma unroll
            for (int j = 0; j < 4; j++)
              if (j < s) {
                f32x4 kj = *(const f32x4*)(&kbuf[j][tid * 4]);
                float a = hstep * A2[s][j];
                #pragma unroll
                for (int r = 0; r < 4; r++) z[r] = __builtin_fmaf(a, kj[r], z[r]);
              }
          } else {
            f32x4 k0 = *(const f32x4*)(&kbuf[0][tid * 4]);
            f32x4 k2 = *(const f32x4*)(&kbuf[2][tid * 4]);
            f32x4 k3 = *(const f32x4*)(&kbuf[3][tid * 4]);
            f32x4 k4 = *(const f32x4*)(&kbuf[4][tid * 4]);
            #pragma unroll
            for (int r = 0; r < 4; r++) {
              float d = BW0 * k0[r] + BW2 * k2[r] + BW3 * k3[r] +
                        BW4 * k4[r] + BW5 * kc[r];
              yc[r] += hstep * d;
              z[r] = yc[r];   // z_0 of the next step (or bijector) is y itself
            }
          }
          uint2 pv;
          pv.x = pk2(z[0], z[1]);
          pv.y = pk2(z[2], z[3]);
          *(uint2*)(zA + zw) = pv;
        }
        __syncthreads();
      } // stages
    } // steps
  } // bijectors

  if (wave < 4 && cl < 8)
    *(f32x4*)(out + (row0 + cl) * 64 + dl3) = yc;
}

extern "C" void kernel_launch(void* const* d_in, const int* in_sizes, int n_in,
                              void* d_out, int out_size, void* d_ws, size_t ws_size,
                              hipStream_t stream) {
  (void)in_sizes; (void)n_in; (void)out_size; (void)ws_size;
  const float* x   = (const float*)d_in[0];
  const float* W1a = (const float*)d_in[1];
  const float* b1a = (const float*)d_in[2];
  const float* W2a = (const float*)d_in[3];
  const float* b2a = (const float*)d_in[4];
  const float* W3a = (const float*)d_in[5];
  const float* b3a = (const float*)d_in[6];
  const float* W1b = (const float*)d_in[7];
  const float* b1b = (const float*)d_in[8];
  const float* W2b = (const float*)d_in[9];
  const float* b2b = (const float*)d_in[10];
  const float* W3b = (const float*)d_in[11];
  const float* b3b = (const float*)d_in[12];
  unsigned short* ws = (unsigned short*)d_ws;
  float* out = (float*)d_out;

  hipLaunchKernelGGL(ffjord_setup, dim3(96), dim3(256), 0, stream,
                     W1a, W2a, W3a, W1b, W2b, W3b, ws);
  hipLaunchKernelGGL(ffjord_main, dim3(512), dim3(512), 0, stream,
                     x, out, ws, W1a, b1a, b2a, b3a, W1b, b1b, b2b, b3b);
}

// Round 13
// 332.963 us; speedup vs baseline: 3.3331x; 3.3331x over previous
//
#include <hip/hip_runtime.h>

typedef __attribute__((ext_vector_type(8))) short short8;
typedef __attribute__((ext_vector_type(4))) float f32x4;

#define NSTEPS 16

__device__ __forceinline__ unsigned short bf16rne(float f) {
  unsigned int u = __float_as_uint(f);
  u += 0x7FFFu + ((u >> 16) & 1u);
  return (unsigned short)(u >> 16);
}

#if __has_builtin(__builtin_amdgcn_cvt_pk_bf16_f32)
typedef __attribute__((ext_vector_type(2))) __bf16 v2bf16;
__device__ __forceinline__ unsigned int pk2(float a, float b) {
  v2bf16 t = __builtin_amdgcn_cvt_pk_bf16_f32(a, b);
  unsigned int r;
  __builtin_memcpy(&r, &t, 4);
  return r;
}
#else
__device__ __forceinline__ unsigned int pk2(float a, float b) {
  unsigned int ua = __float_as_uint(a), ub = __float_as_uint(b);
  ua += 0x7FFFu + ((ua >> 16) & 1u);
  ub += 0x7FFFu + ((ub >> 16) & 1u);
  return (ua >> 16) | (ub & 0xFFFF0000u);
}
#endif

__device__ __forceinline__ float tanh_fast(float x) {
  // tanh(x) = 1 - 2/(e^{2x}+1); e->inf => 1, e->0 => -1 (no clamp needed)
  float e = __builtin_amdgcn_exp2f(x * 2.8853900817779268f);
  return __builtin_fmaf(-2.0f, __builtin_amdgcn_rcpf(e + 1.0f), 1.0f);
}

// Pre-shuffle fp32 weights -> bf16 MFMA fragments (B-frag of W == A-frag of W^T).
// lane holds W[k = 32*ks + 8*(lane>>4) + j][c = 16*t + (lane&15)], j=0..7
__global__ void ffjord_setup(const float* __restrict__ W1a, const float* __restrict__ W2a,
                             const float* __restrict__ W3a, const float* __restrict__ W1b,
                             const float* __restrict__ W2b, const float* __restrict__ W3b,
                             unsigned short* __restrict__ ws) {
  int gid = blockIdx.x * blockDim.x + threadIdx.x;   // 0..24575
  int bij = gid / 12288;
  int r = gid - bij * 12288;
  const float* W1 = bij ? W1b : W1a;
  const float* W2 = bij ? W2b : W2a;
  const float* W3 = bij ? W3b : W3a;
  unsigned short* o = ws + bij * 98304;
  const float* src;
  int kstride;
  if (r < 2048) {                 // W1f
    int lane = r & 63, nt = (r >> 6) & 15, ks = r >> 10;
    int k0 = ks * 32 + (lane >> 4) * 8, n = nt * 16 + (lane & 15);
    src = W1 + k0 * 256 + n; kstride = 256; o += r * 8;
  } else if (r < 10240) {         // W2f
    int rr = r - 2048;
    int lane = rr & 63, nt = (rr >> 6) & 15, ks = rr >> 10;
    int k0 = ks * 32 + (lane >> 4) * 8, n = nt * 16 + (lane & 15);
    src = W2 + k0 * 256 + n; kstride = 256; o += 16384 + rr * 8;
  } else {                        // W3f
    int rr = r - 10240;
    int lane = rr & 63, nt = (rr >> 6) & 3, ks = rr >> 8;
    int k0 = ks * 32 + (lane >> 4) * 8, n = nt * 16 + (lane & 15);
    src = W3 + k0 * 64 + n; kstride = 64; o += 81920 + rr * 8;
  }
  #pragma unroll
  for (int j = 0; j < 8; j++) o[j] = bf16rne(src[j * kstride]);
}

// 1024 threads / 16 waves, 16 batch rows per block, grid 256 (1 block/CU).
// Wave w = m-tile w of L1/L2 (W1/W2 frags in registers). L3 on waves 0-3:
// full K=256 with W3 frags in REGISTERS (w3f[8], statically indexed,
// read-only — the kbuf trick keeps the RK k-history in LDS, which is what
// prevented R6/R8's spill). RK waves keep only the y-slice in registers and
// emit the next stage input z_{s+1} directly as bf16 A-frags.
// 3 barriers/stage; LDS ~39.4 KB.
__global__ __launch_bounds__(1024, 4) void ffjord_main(
    const float* __restrict__ x, float* __restrict__ out,
    const unsigned short* __restrict__ ws,
    const float* __restrict__ W1a, const float* __restrict__ b1a,
    const float* __restrict__ b2a, const float* __restrict__ b3a,
    const float* __restrict__ W1b, const float* __restrict__ b1b,
    const float* __restrict__ b2b, const float* __restrict__ b3b) {
  // zA: 8 groups of (16 rows x 8 j) ushorts, each group padded 256B->272B
  __shared__ __align__(16) unsigned short zA[1088];
  __shared__ __align__(16) unsigned short h1A[4096];   // [g8][row16][j8]
  __shared__ __align__(16) unsigned short h2A[4096];
  __shared__ __align__(16) float kbuf[5][1024];        // k_0..k_4 (RK waves, 20 KB)

  const int tid = threadIdx.x;
  const int wave = tid >> 6;        // 0..15
  const int lane = tid & 63;
  const int cl = lane & 15;
  const int qd = lane >> 4;
  const int row0 = blockIdx.x * 16;

  // L1/L2 output tile: wave w owns hidden dims [w*16, w*16+16)
  const int c0 = wave * 16 + qd * 4;
  const int hoff = (c0 >> 5) * 512 + ((c0 & 31) >> 3) * 128 + cl * 8 + (c0 & 7);
  // z A-frag read base (second frag at +544 ushorts)
  const int zrb = qd * 136 + cl * 8;
  // L3 thread coords (waves 0-3): dims dl3..dl3+3 of batch row cl
  const int w3i = wave & 3;
  const int dl3 = w3i * 16 + qd * 4;
  // z-frag write slot for those 4 dims (b64-aligned)
  const int zw = (2 * w3i + (qd >> 1)) * 136 + cl * 8 + 4 * (qd & 1);

  const float hstep = 1.0f / 16.0f;

  f32x4 yc;           // private y slice (4 dims x 1 row), waves 0-3

  // A2[s] = DOPRI a_{s+1,j} coefficients (z for stage s+1 built at stage s);
  // row s has entries j=0..s (diag = coefficient of k_s).
  const float A2[5][5] = {
      {1.f / 5.f, 0.f, 0.f, 0.f, 0.f},
      {3.f / 40.f, 9.f / 40.f, 0.f, 0.f, 0.f},
      {44.f / 45.f, -56.f / 15.f, 32.f / 9.f, 0.f, 0.f},
      {19372.f / 6561.f, -25360.f / 2187.f, 64448.f / 6561.f, -212.f / 729.f, 0.f},
      {9017.f / 3168.f, -355.f / 33.f, 46732.f / 5247.f, 49.f / 176.f, -5103.f / 18656.f}};
  const float CT[6] = {0.0f, 0.2f, 0.3f, 0.8f, 8.0f / 9.0f, 1.0f};
  const float BW0 = 35.f / 384.f, BW2 = 500.f / 1113.f, BW3 = 125.f / 192.f,
              BW4 = -2187.f / 6784.f, BW5 = 11.f / 84.f;

  for (int bij = 0; bij < 2; bij++) {
    const unsigned short* wsb = ws + bij * 98304;
    const float* W1 = bij ? W1b : W1a;
    const float* b1 = bij ? b1b : b1a;
    const float* b2 = bij ? b2b : b2a;
    const float* b3 = bij ? b3b : b3a;

    f32x4 b1c = *(const f32x4*)(b1 + c0);
    f32x4 w1t4 = *(const f32x4*)(W1 + 64 * 256 + c0);
    f32x4 b2c = *(const f32x4*)(b2 + c0);
    f32x4 b3c = *(const f32x4*)(b3 + dl3);

    // register-resident W1/W2 fragments (A-operand of W^T)
    const short8* w1p = (const short8*)wsb;
    const short8* w2p = (const short8*)(wsb + 16384);
    const short8* w3p = (const short8*)(wsb + 81920);
    short8 w1f[2];
    #pragma unroll
    for (int ks = 0; ks < 2; ks++)
      w1f[ks] = w1p[(ks * 16 + wave) * 64 + lane];
    short8 w2f[8];
    #pragma unroll
    for (int ks = 0; ks < 8; ks++)
      w2f[ks] = w2p[(ks * 16 + wave) * 64 + lane];
    // W3 fragments in registers on the L3 waves
    short8 w3f[8];
    if (wave < 4) {
      #pragma unroll
      for (int ks = 0; ks < 8; ks++)
        w3f[ks] = w3p[(ks * 4 + w3i) * 64 + lane];
    }

    if (bij == 0 && wave < 4) {
      // init private y slice from x and publish z_0 = y as bf16 A-frags
      yc = *(const f32x4*)(x + (row0 + cl) * 64 + dl3);
      uint2 pv;
      pv.x = pk2(yc[0], yc[1]);
      pv.y = pk2(yc[2], yc[3]);
      *(uint2*)(zA + zw) = pv;
    }
    // bij 1: y-frag was already published by the last stage-5 L3 below
    __syncthreads();

    for (int step = 0; step < NSTEPS; step++) {
      float stepf = (float)step;
      #pragma unroll
      for (int s = 0; s < 6; s++) {
        float ts = (stepf + CT[s]) * hstep;

        // ---- layer 1: h1 = tanh(W1^T z_s + b1 + t*W1t), K=64
        {
          short8 a0 = *(const short8*)(zA + zrb);
          short8 a1 = *(const short8*)(zA + zrb + 544);
          f32x4 acc;
          #pragma unroll
          for (int r = 0; r < 4; r++)
            acc[r] = __builtin_fmaf(ts, w1t4[r], b1c[r]);
          acc = __builtin_amdgcn_mfma_f32_16x16x32_bf16(w1f[0], a0, acc, 0, 0, 0);
          acc = __builtin_amdgcn_mfma_f32_16x16x32_bf16(w1f[1], a1, acc, 0, 0, 0);
          uint2 pv;
          pv.x = pk2(tanh_fast(acc[0]), tanh_fast(acc[1]));
          pv.y = pk2(tanh_fast(acc[2]), tanh_fast(acc[3]));
          *(uint2*)(h1A + hoff) = pv;
        }
        __syncthreads();

        // ---- layer 2: h2 = tanh(W2^T h1 + b2), K=256, 2 chains of 4
        {
          f32x4 accA = b2c;
          f32x4 accB; accB[0] = 0.f; accB[1] = 0.f; accB[2] = 0.f; accB[3] = 0.f;
          #pragma unroll
          for (int ks = 0; ks < 4; ks++) {
            short8 hb = ((const short8*)h1A)[ks * 64 + lane];
            accA = __builtin_amdgcn_mfma_f32_16x16x32_bf16(w2f[ks], hb, accA, 0, 0, 0);
          }
          #pragma unroll
          for (int ks = 4; ks < 8; ks++) {
            short8 hb = ((const short8*)h1A)[ks * 64 + lane];
            accB = __builtin_amdgcn_mfma_f32_16x16x32_bf16(w2f[ks], hb, accB, 0, 0, 0);
          }
          uint2 pv;
          pv.x = pk2(tanh_fast(accA[0] + accB[0]), tanh_fast(accA[1] + accB[1]));
          pv.y = pk2(tanh_fast(accA[2] + accB[2]), tanh_fast(accA[3] + accB[3]));
          *(uint2*)(h2A + hoff) = pv;
        }
        __syncthreads();

        // ---- layer 3 + RK bookkeeping, waves 0-3 only:
        // k_s = W3^T h2 + b3 (full K=256, W3 in registers); k-history in kbuf
        // (wave-private, no barrier); emit z_{s+1} (or update y) as bf16 A-frags.
        if (wave < 4) {
          f32x4 accP = b3c;
          f32x4 accQ; accQ[0] = 0.f; accQ[1] = 0.f; accQ[2] = 0.f; accQ[3] = 0.f;
          #pragma unroll
          for (int ks = 0; ks < 8; ks += 2) {
            short8 hb0 = ((const short8*)h2A)[ks * 64 + lane];
            short8 hb1 = ((const short8*)h2A)[(ks + 1) * 64 + lane];
            accP = __builtin_amdgcn_mfma_f32_16x16x32_bf16(w3f[ks], hb0, accP, 0, 0, 0);
            accQ = __builtin_amdgcn_mfma_f32_16x16x32_bf16(w3f[ks + 1], hb1, accQ, 0, 0, 0);
          }
          f32x4 kc;
          #pragma unroll
          for (int r = 0; r < 4; r++) kc[r] = accP[r] + accQ[r];
          if (s < 5) *(f32x4*)(&kbuf[s][tid * 4]) = kc;   // k_5 never re-read

          f32x4 z;
          if (s < 5) {
            #pragma unroll
            for (int r = 0; r < 4; r++)
              z[r] = __builtin_fmaf(hstep * A2[s][s], kc[r], yc[r]);
            #pragma unroll
            for (int j = 0; j < 4; j++)
              if (j < s) {
                f32x4 kj = *(const f32x4*)(&kbuf[j][tid * 4]);
                float a = hstep * A2[s][j];
                #pragma unroll
                for (int r = 0; r < 4; r++) z[r] = __builtin_fmaf(a, kj[r], z[r]);
              }
          } else {
            f32x4 k0 = *(const f32x4*)(&kbuf[0][tid * 4]);
            f32x4 k2 = *(const f32x4*)(&kbuf[2][tid * 4]);
            f32x4 k3 = *(const f32x4*)(&kbuf[3][tid * 4]);
            f32x4 k4 = *(const f32x4*)(&kbuf[4][tid * 4]);
            #pragma unroll
            for (int r = 0; r < 4; r++) {
              float d = BW0 * k0[r] + BW2 * k2[r] + BW3 * k3[r] +
                        BW4 * k4[r] + BW5 * kc[r];
              yc[r] += hstep * d;
              z[r] = yc[r];   // z_0 of the next step (or bijector) is y itself
            }
          }
          uint2 pv;
          pv.x = pk2(z[0], z[1]);
          pv.y = pk2(z[2], z[3]);
          *(uint2*)(zA + zw) = pv;
        }
        __syncthreads();
      } // stages
    } // steps
  } // bijectors

  if (wave < 4)
    *(f32x4*)(out + (row0 + cl) * 64 + dl3) = yc;
}

extern "C" void kernel_launch(void* const* d_in, const int* in_sizes, int n_in,
                              void* d_out, int out_size, void* d_ws, size_t ws_size,
                              hipStream_t stream) {
  (void)in_sizes; (void)n_in; (void)out_size; (void)ws_size;
  const float* x   = (const float*)d_in[0];
  const float* W1a = (const float*)d_in[1];
  const float* b1a = (const float*)d_in[2];
  const float* W2a = (const float*)d_in[3];
  const float* b2a = (const float*)d_in[4];
  const float* W3a = (const float*)d_in[5];
  const float* b3a = (const float*)d_in[6];
  const float* W1b = (const float*)d_in[7];
  const float* b1b = (const float*)d_in[8];
  const float* W2b = (const float*)d_in[9];
  const float* b2b = (const float*)d_in[10];
  const float* W3b = (const float*)d_in[11];
  const float* b3b = (const float*)d_in[12];
  unsigned short* ws = (unsigned short*)d_ws;
  float* out = (float*)d_out;

  hipLaunchKernelGGL(ffjord_setup, dim3(96), dim3(256), 0, stream,
                     W1a, W2a, W3a, W1b, W2b, W3b, ws);
  hipLaunchKernelGGL(ffjord_main, dim3(256), dim3(1024), 0, stream,
                     x, out, ws, W1a, b1a, b2a, b3a, W1b, b1b, b2b, b3b);
}

// Round 15
// 320.015 us; speedup vs baseline: 3.4680x; 1.0405x over previous
//
#include <hip/hip_runtime.h>

typedef __attribute__((ext_vector_type(8))) short short8;
typedef __attribute__((ext_vector_type(4))) float f32x4;

#define NSTEPS 16

__device__ __forceinline__ unsigned short bf16rne(float f) {
  unsigned int u = __float_as_uint(f);
  u += 0x7FFFu + ((u >> 16) & 1u);
  return (unsigned short)(u >> 16);
}

#if __has_builtin(__builtin_amdgcn_cvt_pk_bf16_f32)
typedef __attribute__((ext_vector_type(2))) __bf16 v2bf16;
__device__ __forceinline__ unsigned int pk2(float a, float b) {
  v2bf16 t = __builtin_amdgcn_cvt_pk_bf16_f32(a, b);
  unsigned int r;
  __builtin_memcpy(&r, &t, 4);
  return r;
}
#else
__device__ __forceinline__ unsigned int pk2(float a, float b) {
  unsigned int ua = __float_as_uint(a), ub = __float_as_uint(b);
  ua += 0x7FFFu + ((ua >> 16) & 1u);
  ub += 0x7FFFu + ((ub >> 16) & 1u);
  return (ua >> 16) | (ub & 0xFFFF0000u);
}
#endif

__device__ __forceinline__ float tanh_fast(float x) {
  // tanh(x) = 1 - 2/(e^{2x}+1); e->inf => 1, e->0 => -1 (no clamp needed)
  float e = __builtin_amdgcn_exp2f(x * 2.8853900817779268f);
  return __builtin_fmaf(-2.0f, __builtin_amdgcn_rcpf(e + 1.0f), 1.0f);
}

// Pre-shuffle fp32 weights -> bf16 MFMA fragments (B-frag of W == A-frag of W^T).
// lane holds W[k = 32*ks + 8*(lane>>4) + j][c = 16*t + (lane&15)], j=0..7
__global__ void ffjord_setup(const float* __restrict__ W1a, const float* __restrict__ W2a,
                             const float* __restrict__ W3a, const float* __restrict__ W1b,
                             const float* __restrict__ W2b, const float* __restrict__ W3b,
                             unsigned short* __restrict__ ws) {
  int gid = blockIdx.x * blockDim.x + threadIdx.x;   // 0..24575
  int bij = gid / 12288;
  int r = gid - bij * 12288;
  const float* W1 = bij ? W1b : W1a;
  const float* W2 = bij ? W2b : W2a;
  const float* W3 = bij ? W3b : W3a;
  unsigned short* o = ws + bij * 98304;
  const float* src;
  int kstride;
  if (r < 2048) {                 // W1f
    int lane = r & 63, nt = (r >> 6) & 15, ks = r >> 10;
    int k0 = ks * 32 + (lane >> 4) * 8, n = nt * 16 + (lane & 15);
    src = W1 + k0 * 256 + n; kstride = 256; o += r * 8;
  } else if (r < 10240) {         // W2f
    int rr = r - 2048;
    int lane = rr & 63, nt = (rr >> 6) & 15, ks = rr >> 10;
    int k0 = ks * 32 + (lane >> 4) * 8, n = nt * 16 + (lane & 15);
    src = W2 + k0 * 256 + n; kstride = 256; o += 16384 + rr * 8;
  } else {                        // W3f
    int rr = r - 10240;
    int lane = rr & 63, nt = (rr >> 6) & 3, ks = rr >> 8;
    int k0 = ks * 32 + (lane >> 4) * 8, n = nt * 16 + (lane & 15);
    src = W3 + k0 * 64 + n; kstride = 64; o += 81920 + rr * 8;
  }
  #pragma unroll
  for (int j = 0; j < 8; j++) o[j] = bf16rne(src[j * kstride]);
}

// 1024 threads / 16 waves, 16 batch rows per block, grid 256 (1 block/CU).
// Wave w = m-tile w of L1/L2 (W1/W2 frags in registers). L3 on waves 0-3:
// full K=256, W3 frags from LDS (both bijectors resident — copy hoisted out
// of the bijector loop), RK k-history in LDS kbuf[5][1024] indexed tid*4
// (wave-private slots, no barrier; registers would spill: proven R6/R8/R13),
// y-slice in registers; next-stage z emitted directly as bf16 A-frags.
// 3 barriers/stage.
__global__ __launch_bounds__(1024, 4) void ffjord_main(
    const float* __restrict__ x, float* __restrict__ out,
    const unsigned short* __restrict__ ws,
    const float* __restrict__ W1a, const float* __restrict__ b1a,
    const float* __restrict__ b2a, const float* __restrict__ b3a,
    const float* __restrict__ W1b, const float* __restrict__ b1b,
    const float* __restrict__ b2b, const float* __restrict__ b3b) {
  // zA: 8 groups of (16 rows x 8 j) ushorts, each group padded 256B->272B
  __shared__ __align__(16) unsigned short zA[1088];
  __shared__ __align__(16) unsigned short h1A[4096];   // [g8][row16][j8]
  __shared__ __align__(16) unsigned short h2A[4096];
  __shared__ __align__(16) unsigned short w3s[2][16384]; // W3 frags, both bijectors (64 KB)
  __shared__ __align__(16) float kbuf[5][1024];        // k_0..k_4 (waves 0-3, 20 KB)

  const int tid = threadIdx.x;
  const int wave = tid >> 6;        // 0..15
  const int lane = tid & 63;
  const int cl = lane & 15;
  const int qd = lane >> 4;
  const int row0 = blockIdx.x * 16;

  // L1/L2 output tile: wave w owns hidden dims [w*16, w*16+16)
  const int c0 = wave * 16 + qd * 4;
  const int hoff = (c0 >> 5) * 512 + ((c0 & 31) >> 3) * 128 + cl * 8 + (c0 & 7);
  // z A-frag read base (second frag at +544 ushorts)
  const int zrb = qd * 136 + cl * 8;
  // L3 thread coords (waves 0-3): dims dl3..dl3+3 of batch row cl
  const int w3i = wave & 3;
  const int dl3 = w3i * 16 + qd * 4;
  // z-frag write slot for those 4 dims (b64-aligned)
  const int zw = (2 * w3i + (qd >> 1)) * 136 + cl * 8 + 4 * (qd & 1);

  const float hstep = 1.0f / 16.0f;

  f32x4 yc;           // private y slice (4 dims x 1 row), waves 0-3

  // A2[s] = DOPRI a_{s+1,j} coefficients (z for stage s+1 built at stage s);
  // row s has entries j=0..s (diag = coefficient of k_s).
  const float A2[5][5] = {
      {1.f / 5.f, 0.f, 0.f, 0.f, 0.f},
      {3.f / 40.f, 9.f / 40.f, 0.f, 0.f, 0.f},
      {44.f / 45.f, -56.f / 15.f, 32.f / 9.f, 0.f, 0.f},
      {19372.f / 6561.f, -25360.f / 2187.f, 64448.f / 6561.f, -212.f / 729.f, 0.f},
      {9017.f / 3168.f, -355.f / 33.f, 46732.f / 5247.f, 49.f / 176.f, -5103.f / 18656.f}};
  const float CT[6] = {0.0f, 0.2f, 0.3f, 0.8f, 8.0f / 9.0f, 1.0f};
  const float BW0 = 35.f / 384.f, BW2 = 500.f / 1113.f, BW3 = 125.f / 192.f,
              BW4 = -2187.f / 6784.f, BW5 = 11.f / 84.f;

  // W3 fragments for BOTH bijectors -> LDS once (4096 uint4)
  {
    const uint4* s0 = (const uint4*)(ws + 81920);
    const uint4* s1 = (const uint4*)(ws + 98304 + 81920);
    uint4* d0 = (uint4*)&w3s[0][0];
    uint4* d1 = (uint4*)&w3s[1][0];
    d0[tid] = s0[tid];
    d0[tid + 1024] = s0[tid + 1024];
    d1[tid] = s1[tid];
    d1[tid + 1024] = s1[tid + 1024];
  }

  for (int bij = 0; bij < 2; bij++) {
    const unsigned short* wsb = ws + bij * 98304;
    const float* W1 = bij ? W1b : W1a;
    const float* b1 = bij ? b1b : b1a;
    const float* b2 = bij ? b2b : b2a;
    const float* b3 = bij ? b3b : b3a;

    f32x4 b1c = *(const f32x4*)(b1 + c0);
    f32x4 w1t4 = *(const f32x4*)(W1 + 64 * 256 + c0);
    f32x4 b2c = *(const f32x4*)(b2 + c0);
    f32x4 b3c = *(const f32x4*)(b3 + dl3);

    // register-resident W1/W2 fragments (A-operand of W^T)
    const short8* w1p = (const short8*)wsb;
    const short8* w2p = (const short8*)(wsb + 16384);
    short8 w1f[2];
    #pragma unroll
    for (int ks = 0; ks < 2; ks++)
      w1f[ks] = w1p[(ks * 16 + wave) * 64 + lane];
    short8 w2f[8];
    #pragma unroll
    for (int ks = 0; ks < 8; ks++)
      w2f[ks] = w2p[(ks * 16 + wave) * 64 + lane];

    const short8* w3c = (const short8*)&w3s[bij][0];

    if (bij == 0 && wave < 4) {
      // init private y slice from x and publish z_0 = y as bf16 A-frags
      yc = *(const f32x4*)(x + (row0 + cl) * 64 + dl3);
      uint2 pv;
      pv.x = pk2(yc[0], yc[1]);
      pv.y = pk2(yc[2], yc[3]);
      *(uint2*)(zA + zw) = pv;
    }
    // bij 1: y-frag was already published by the last stage-5 L3 below
    __syncthreads();

    for (int step = 0; step < NSTEPS; step++) {
      float stepf = (float)step;
      #pragma unroll
      for (int s = 0; s < 6; s++) {
        float ts = (stepf + CT[s]) * hstep;

        // ---- layer 1: h1 = tanh(W1^T z_s + b1 + t*W1t), K=64
        {
          short8 a0 = *(const short8*)(zA + zrb);
          short8 a1 = *(const short8*)(zA + zrb + 544);
          f32x4 acc;
          #pragma unroll
          for (int r = 0; r < 4; r++)
            acc[r] = __builtin_fmaf(ts, w1t4[r], b1c[r]);
          acc = __builtin_amdgcn_mfma_f32_16x16x32_bf16(w1f[0], a0, acc, 0, 0, 0);
          acc = __builtin_amdgcn_mfma_f32_16x16x32_bf16(w1f[1], a1, acc, 0, 0, 0);
          uint2 pv;
          pv.x = pk2(tanh_fast(acc[0]), tanh_fast(acc[1]));
          pv.y = pk2(tanh_fast(acc[2]), tanh_fast(acc[3]));
          *(uint2*)(h1A + hoff) = pv;
        }
        __syncthreads();

        // ---- layer 2: h2 = tanh(W2^T h1 + b2), K=256, 2 chains of 4
        {
          f32x4 accA = b2c;
          f32x4 accB; accB[0] = 0.f; accB[1] = 0.f; accB[2] = 0.f; accB[3] = 0.f;
          #pragma unroll
          for (int ks = 0; ks < 4; ks++) {
            short8 hb = ((const short8*)h1A)[ks * 64 + lane];
            accA = __builtin_amdgcn_mfma_f32_16x16x32_bf16(w2f[ks], hb, accA, 0, 0, 0);
          }
          #pragma unroll
          for (int ks = 4; ks < 8; ks++) {
            short8 hb = ((const short8*)h1A)[ks * 64 + lane];
            accB = __builtin_amdgcn_mfma_f32_16x16x32_bf16(w2f[ks], hb, accB, 0, 0, 0);
          }
          uint2 pv;
          pv.x = pk2(tanh_fast(accA[0] + accB[0]), tanh_fast(accA[1] + accB[1]));
          pv.y = pk2(tanh_fast(accA[2] + accB[2]), tanh_fast(accA[3] + accB[3]));
          *(uint2*)(h2A + hoff) = pv;
        }
        __syncthreads();

        // ---- layer 3 + RK bookkeeping, waves 0-3 only:
        // k_s = W3^T h2 + b3 (full K=256, W3 from LDS); k-history in kbuf
        // (wave-private, no barrier); emit z_{s+1} (or update y) as bf16 A-frags.
        if (wave < 4) {
          f32x4 accP = b3c;
          f32x4 accQ; accQ[0] = 0.f; accQ[1] = 0.f; accQ[2] = 0.f; accQ[3] = 0.f;
          #pragma unroll
          for (int ks = 0; ks < 8; ks += 2) {
            short8 hb0 = ((const short8*)h2A)[ks * 64 + lane];
            short8 wf0 = w3c[(ks * 4 + w3i) * 64 + lane];
            short8 hb1 = ((const short8*)h2A)[(ks + 1) * 64 + lane];
            short8 wf1 = w3c[((ks + 1) * 4 + w3i) * 64 + lane];
            accP = __builtin_amdgcn_mfma_f32_16x16x32_bf16(wf0, hb0, accP, 0, 0, 0);
            accQ = __builtin_amdgcn_mfma_f32_16x16x32_bf16(wf1, hb1, accQ, 0, 0, 0);
          }
          f32x4 kc;
          #pragma unroll
          for (int r = 0; r < 4; r++) kc[r] = accP[r] + accQ[r];
          if (s < 5) *(f32x4*)(&kbuf[s][tid * 4]) = kc;   // k_5 never re-read

          f32x4 z;
          if (s < 5) {
            #pragma unroll
            for (int r = 0; r < 4; r++)
              z[r] = __builtin_fmaf(hstep * A2[s][s], kc[r], yc[r]);
            #pragma unroll
            for (int j = 0; j < 4; j++)
              if (j < s) {
                f32x4 kj = *(const f32x4*)(&kbuf[j][tid * 4]);
                float a = hstep * A2[s][j];
                #pragma unroll
                for (int r = 0; r < 4; r++) z[r] = __builtin_fmaf(a, kj[r], z[r]);
              }
          } else {
            f32x4 k0 = *(const f32x4*)(&kbuf[0][tid * 4]);
            f32x4 k2 = *(const f32x4*)(&kbuf[2][tid * 4]);
            f32x4 k3 = *(const f32x4*)(&kbuf[3][tid * 4]);
            f32x4 k4 = *(const f32x4*)(&kbuf[4][tid * 4]);
            #pragma unroll
            for (int r = 0; r < 4; r++) {
              float d = BW0 * k0[r] + BW2 * k2[r] + BW3 * k3[r] +
                        BW4 * k4[r] + BW5 * kc[r];
              yc[r] += hstep * d;
              z[r] = yc[r];   // z_0 of the next step (or bijector) is y itself
            }
          }
          uint2 pv;
          pv.x = pk2(z[0], z[1]);
          pv.y = pk2(z[2], z[3]);
          *(uint2*)(zA + zw) = pv;
        }
        __syncthreads();
      } // stages
    } // steps
  } // bijectors

  if (wave < 4)
    *(f32x4*)(out + (row0 + cl) * 64 + dl3) = yc;
}

extern "C" void kernel_launch(void* const* d_in, const int* in_sizes, int n_in,
                              void* d_out, int out_size, void* d_ws, size_t ws_size,
                              hipStream_t stream) {
  (void)in_sizes; (void)n_in; (void)out_size; (void)ws_size;
  const float* x   = (const float*)d_in[0];
  const float* W1a = (const float*)d_in[1];
  const float* b1a = (const float*)d_in[2];
  const float* W2a = (const float*)d_in[3];
  const float* b2a = (const float*)d_in[4];
  const float* W3a = (const float*)d_in[5];
  const float* b3a = (const float*)d_in[6];
  const float* W1b = (const float*)d_in[7];
  const float* b1b = (const float*)d_in[8];
  const float* W2b = (const float*)d_in[9];
  const float* b2b = (const float*)d_in[10];
  const float* W3b = (const float*)d_in[11];
  const float* b3b = (const float*)d_in[12];
  unsigned short* ws = (unsigned short*)d_ws;
  float* out = (float*)d_out;

  hipLaunchKernelGGL(ffjord_setup, dim3(96), dim3(256), 0, stream,
                     W1a, W2a, W3a, W1b, W2b, W3b, ws);
  hipLaunchKernelGGL(ffjord_main, dim3(256), dim3(1024), 0, stream,
                     x, out, ws, W1a, b1a, b2a, b3a, W1b, b1b, b2b, b3b);
}